// Round 1
// baseline (1787.513 us; speedup 1.0000x reference)
//
#include <hip/hip_runtime.h>
#include <hip/hip_bf16.h>

#define N_NODES 100000
#define N_EDGES 1600000
#define N_GRAPHS 2000
#define D_IN 600
#define D_H 300
#define D_OUT 2

// ---------------- degree counting ----------------
__global__ __launch_bounds__(256) void count_deg(const int* __restrict__ src,
                                                 const int* __restrict__ dst,
                                                 int* __restrict__ deg_out,
                                                 int* __restrict__ deg_in) {
    int e = blockIdx.x * blockDim.x + threadIdx.x;
    if (e < N_EDGES) {
        atomicAdd(&deg_out[src[e]], 1);
        atomicAdd(&deg_in[dst[e]], 1);
    }
}

// ---------------- per-block sums of deg_in ----------------
__global__ __launch_bounds__(256) void block_sum(const int* __restrict__ deg_in,
                                                 int* __restrict__ bsum) {
    __shared__ int s[256];
    int i = blockIdx.x * 256 + threadIdx.x;
    s[threadIdx.x] = (i < N_NODES) ? deg_in[i] : 0;
    __syncthreads();
    for (int off = 128; off; off >>= 1) {
        if (threadIdx.x < off) s[threadIdx.x] += s[threadIdx.x + off];
        __syncthreads();
    }
    if (threadIdx.x == 0) bsum[blockIdx.x] = s[0];
}

// ---------------- serial scan over block sums (tiny) ----------------
__global__ void scan_serial(const int* __restrict__ bsum, int* __restrict__ boff, int nb) {
    if (threadIdx.x == 0 && blockIdx.x == 0) {
        int run = 0;
        for (int i = 0; i < nb; ++i) { boff[i] = run; run += bsum[i]; }
    }
}

// ---------------- per-node CSR offsets + inv-sqrt degrees ----------------
__global__ __launch_bounds__(256) void node_offsets(const int* __restrict__ deg_in,
                                                    const int* __restrict__ deg_out,
                                                    const int* __restrict__ boff,
                                                    int* __restrict__ row_start,
                                                    int* __restrict__ cursor,
                                                    float* __restrict__ inv_in,
                                                    float* __restrict__ inv_out) {
    __shared__ int s[256];
    int i = blockIdx.x * 256 + threadIdx.x;
    int d = (i < N_NODES) ? deg_in[i] : 0;
    s[threadIdx.x] = d;
    __syncthreads();
    // Hillis-Steele inclusive scan
    for (int off = 1; off < 256; off <<= 1) {
        int v = 0;
        if (threadIdx.x >= off) v = s[threadIdx.x - off];
        __syncthreads();
        if (threadIdx.x >= off) s[threadIdx.x] += v;
        __syncthreads();
    }
    if (i < N_NODES) {
        int excl = s[threadIdx.x] - d;
        int rs = boff[blockIdx.x] + excl;
        row_start[i] = rs;
        cursor[i] = rs;
        int di = deg_in[i];
        int dо = 0; // placeholder removed below
        (void)dо;
        int dout = deg_out[i];
        inv_in[i]  = (di   > 0) ? rsqrtf((float)di)   : 0.0f;
        inv_out[i] = (dout > 0) ? rsqrtf((float)dout) : 0.0f;
    }
}

// ---------------- fill CSR adjacency (incoming edges, store src) ----------------
__global__ __launch_bounds__(256) void fill_csr(const int* __restrict__ src,
                                                const int* __restrict__ dst,
                                                int* __restrict__ cursor,
                                                int* __restrict__ adj) {
    int e = blockIdx.x * blockDim.x + threadIdx.x;
    if (e < N_EDGES) {
        int pos = atomicAdd(&cursor[dst[e]], 1);
        adj[pos] = src[e];
    }
}

// ---------------- fp32 tiled GEMM: C[i][j] = (sum_k A[i][k]*B[k][j]) * rowscale[i] ----------------
#define BM 64
#define BN 64
#define BKK 16
__global__ __launch_bounds__(256) void gemm_scale(const float* __restrict__ A,
                                                  const float* __restrict__ B,
                                                  const float* __restrict__ rowscale,
                                                  float* __restrict__ C,
                                                  int M, int K, int N) {
    __shared__ float As[BKK][BM + 4];
    __shared__ float Bs[BKK][BN + 4];
    int tid = threadIdx.x;
    int tx = tid & 15;   // col group (4 cols each)
    int ty = tid >> 4;   // row group (4 rows each)
    int blockRow = blockIdx.y * BM;
    int blockCol = blockIdx.x * BN;

    float acc[4][4] = {};

    int arow = tid >> 2;        // 0..63
    int akq  = (tid & 3) * 4;   // 0,4,8,12
    int bk   = tid >> 4;        // 0..15
    int bcq  = (tid & 15) * 4;  // 0..60

    int ntiles = (K + BKK - 1) / BKK;
    for (int t = 0; t < ntiles; ++t) {
        int k0 = t * BKK;
        // A tile: [BM rows][BKK k]
        {
            int gr = blockRow + arow;
            int gk = k0 + akq;
            float4 v = make_float4(0.f, 0.f, 0.f, 0.f);
            if (gr < M) {
                if (gk + 3 < K) {
                    v = *reinterpret_cast<const float4*>(&A[(long)gr * K + gk]);
                } else {
                    float tmp[4] = {0.f, 0.f, 0.f, 0.f};
                    for (int j = 0; j < 4; ++j)
                        if (gk + j < K) tmp[j] = A[(long)gr * K + gk + j];
                    v = make_float4(tmp[0], tmp[1], tmp[2], tmp[3]);
                }
            }
            As[akq + 0][arow] = v.x;
            As[akq + 1][arow] = v.y;
            As[akq + 2][arow] = v.z;
            As[akq + 3][arow] = v.w;
        }
        // B tile: [BKK k][BN cols]
        {
            int gk = k0 + bk;
            int gc = blockCol + bcq;
            float4 v = make_float4(0.f, 0.f, 0.f, 0.f);
            if (gk < K) {
                if (gc + 3 < N) {
                    v = *reinterpret_cast<const float4*>(&B[(long)gk * N + gc]);
                } else {
                    float tmp[4] = {0.f, 0.f, 0.f, 0.f};
                    for (int j = 0; j < 4; ++j)
                        if (gc + j < N) tmp[j] = B[(long)gk * N + gc + j];
                    v = make_float4(tmp[0], tmp[1], tmp[2], tmp[3]);
                }
            }
            *reinterpret_cast<float4*>(&Bs[bk][bcq]) = v;
        }
        __syncthreads();
#pragma unroll
        for (int k = 0; k < BKK; ++k) {
            float4 a = *reinterpret_cast<const float4*>(&As[k][ty * 4]);
            float4 b = *reinterpret_cast<const float4*>(&Bs[k][tx * 4]);
            float av[4] = {a.x, a.y, a.z, a.w};
            float bv[4] = {b.x, b.y, b.z, b.w};
#pragma unroll
            for (int i = 0; i < 4; ++i)
#pragma unroll
                for (int j = 0; j < 4; ++j) acc[i][j] += av[i] * bv[j];
        }
        __syncthreads();
    }
    // epilogue: scale by rowscale, store
    for (int i = 0; i < 4; ++i) {
        int gr = blockRow + ty * 4 + i;
        if (gr >= M) continue;
        float sc = rowscale[gr];
        for (int j = 0; j < 4; ++j) {
            int gc = blockCol + tx * 4 + j;
            if (gc < N) C[(long)gr * N + gc] = acc[i][j] * sc;
        }
    }
}

// ---------------- aggregation: h[n] = relu(inv_in[n] * sum_{e in CSR(n)} m[adj[e]] + bias) ----------------
__global__ __launch_bounds__(256) void aggregate(const float* __restrict__ m,
                                                 const int* __restrict__ row_start,
                                                 const int* __restrict__ deg_in,
                                                 const int* __restrict__ adj,
                                                 const float* __restrict__ inv_in,
                                                 const float* __restrict__ bias,
                                                 float* __restrict__ h) {
    int wave = (int)((blockIdx.x * (long)blockDim.x + threadIdx.x) >> 6);
    int lane = threadIdx.x & 63;
    if (wave >= N_NODES) return;
    int n = wave;
    int s = row_start[n];
    int d = deg_in[n];
    int c0 = lane, c1 = lane + 64, c2 = lane + 128, c3 = lane + 192, c4 = lane + 256;
    bool v4 = (c4 < D_H);
    float a0 = 0.f, a1 = 0.f, a2 = 0.f, a3 = 0.f, a4 = 0.f;
    for (int e = 0; e < d; ++e) {
        const float* row = m + (long)adj[s + e] * D_H;
        a0 += row[c0];
        a1 += row[c1];
        a2 += row[c2];
        a3 += row[c3];
        if (v4) a4 += row[c4];
    }
    float sc = inv_in[n];
    float* out = h + (long)n * D_H;
    out[c0] = fmaxf(a0 * sc + bias[c0], 0.f);
    out[c1] = fmaxf(a1 * sc + bias[c1], 0.f);
    out[c2] = fmaxf(a2 * sc + bias[c2], 0.f);
    out[c3] = fmaxf(a3 * sc + bias[c3], 0.f);
    if (v4) out[c4] = fmaxf(a4 * sc + bias[c4], 0.f);
}

// ---------------- fc + softmax + pooled sum ----------------
__global__ __launch_bounds__(256) void fc_pool(const float* __restrict__ h,
                                               const float* __restrict__ Wfc,
                                               const float* __restrict__ bfc,
                                               const int* __restrict__ gid,
                                               float* __restrict__ pooled,
                                               int* __restrict__ gcount) {
    int wave = (int)((blockIdx.x * (long)blockDim.x + threadIdx.x) >> 6);
    int lane = threadIdx.x & 63;
    if (wave >= N_NODES) return;
    const float* row = h + (long)wave * D_H;
    float a0 = 0.f, a1 = 0.f;
    for (int c = lane; c < D_H; c += 64) {
        float v = row[c];
        a0 += v * Wfc[c * 2];
        a1 += v * Wfc[c * 2 + 1];
    }
    for (int off = 32; off; off >>= 1) {
        a0 += __shfl_down(a0, off);
        a1 += __shfl_down(a1, off);
    }
    if (lane == 0) {
        float z0 = a0 + bfc[0], z1 = a1 + bfc[1];
        float mx = fmaxf(z0, z1);
        float e0 = __expf(z0 - mx), e1 = __expf(z1 - mx);
        float inv = 1.f / (e0 + e1);
        int g = gid[wave];
        atomicAdd(&pooled[g * 2 + 0], e0 * inv);
        atomicAdd(&pooled[g * 2 + 1], e1 * inv);
        atomicAdd(&gcount[g], 1);
    }
}

// ---------------- finalize: divide by counts ----------------
__global__ __launch_bounds__(256) void finalize(const float* __restrict__ pooled,
                                                const int* __restrict__ gcount,
                                                float* __restrict__ out) {
    int i = blockIdx.x * blockDim.x + threadIdx.x;
    if (i < N_GRAPHS * 2) {
        int g = i >> 1;
        float c = (float)max(gcount[g], 1);
        out[i] = pooled[i] / c;
    }
}

extern "C" void kernel_launch(void* const* d_in, const int* in_sizes, int n_in,
                              void* d_out, int out_size, void* d_ws, size_t ws_size,
                              hipStream_t stream) {
    const float* x   = (const float*)d_in[0];
    const float* W1  = (const float*)d_in[1];
    const float* b1  = (const float*)d_in[2];
    const float* W2  = (const float*)d_in[3];
    const float* b2  = (const float*)d_in[4];
    const float* Wfc = (const float*)d_in[5];
    const float* bfc = (const float*)d_in[6];
    const int* src   = (const int*)d_in[7];
    const int* dst   = (const int*)d_in[8];
    const int* gid   = (const int*)d_in[9];

    char* ws = (char*)d_ws;
    size_t off = 0;
    auto alloc = [&](size_t bytes) -> void* {
        void* p = ws + off;
        off = (off + bytes + 255) & ~(size_t)255;
        return p;
    };
    float* m_buf    = (float*)alloc((size_t)N_NODES * D_H * 4);
    float* h_buf    = (float*)alloc((size_t)N_NODES * D_H * 4);
    int*   adj      = (int*)alloc((size_t)N_EDGES * 4);
    int*   row_st   = (int*)alloc((size_t)N_NODES * 4);
    int*   cursor   = (int*)alloc((size_t)N_NODES * 4);
    int*   deg_in   = (int*)alloc((size_t)N_NODES * 4);
    int*   deg_out  = (int*)alloc((size_t)N_NODES * 4);
    float* inv_in   = (float*)alloc((size_t)N_NODES * 4);
    float* inv_out  = (float*)alloc((size_t)N_NODES * 4);
    const int NB = (N_NODES + 255) / 256;
    int*   bsum     = (int*)alloc((size_t)NB * 4);
    int*   boff     = (int*)alloc((size_t)NB * 4);
    float* pooled   = (float*)alloc((size_t)N_GRAPHS * 2 * 4);
    int*   gcount   = (int*)alloc((size_t)N_GRAPHS * 4);

    hipMemsetAsync(deg_in, 0, (size_t)N_NODES * 4, stream);
    hipMemsetAsync(deg_out, 0, (size_t)N_NODES * 4, stream);
    hipMemsetAsync(pooled, 0, (size_t)N_GRAPHS * 2 * 4, stream);
    hipMemsetAsync(gcount, 0, (size_t)N_GRAPHS * 4, stream);

    count_deg<<<(N_EDGES + 255) / 256, 256, 0, stream>>>(src, dst, deg_out, deg_in);
    block_sum<<<NB, 256, 0, stream>>>(deg_in, bsum);
    scan_serial<<<1, 64, 0, stream>>>(bsum, boff, NB);
    node_offsets<<<NB, 256, 0, stream>>>(deg_in, deg_out, boff, row_st, cursor, inv_in, inv_out);
    fill_csr<<<(N_EDGES + 255) / 256, 256, 0, stream>>>(src, dst, cursor, adj);

    dim3 g1((D_H + BN - 1) / BN, (N_NODES + BM - 1) / BM);
    // layer 1: m = (x @ W1) * inv_out ; h = relu(agg * inv_in + b1)
    gemm_scale<<<g1, 256, 0, stream>>>(x, W1, inv_out, m_buf, N_NODES, D_IN, D_H);
    aggregate<<<(N_NODES * 64 + 255) / 256, 256, 0, stream>>>(m_buf, row_st, deg_in, adj, inv_in, b1, h_buf);
    // layer 2
    gemm_scale<<<g1, 256, 0, stream>>>(h_buf, W2, inv_out, m_buf, N_NODES, D_H, D_H);
    aggregate<<<(N_NODES * 64 + 255) / 256, 256, 0, stream>>>(m_buf, row_st, deg_in, adj, inv_in, b2, h_buf);
    // head
    fc_pool<<<(N_NODES * 64 + 255) / 256, 256, 0, stream>>>(h_buf, Wfc, bfc, gid, pooled, gcount);
    finalize<<<(N_GRAPHS * 2 + 255) / 256, 256, 0, stream>>>(pooled, gcount, (float*)d_out);
}

// Round 2
// 1028.011 us; speedup vs baseline: 1.7388x; 1.7388x over previous
//
#include <hip/hip_runtime.h>
#include <hip/hip_bf16.h>

#define N_NODES 100000
#define N_EDGES 1600000
#define N_GRAPHS 2000
#define D_IN 600
#define D_H 300
#define D_OUT 2

#define NPAD 320        // padded hidden width (multiple of 64)
#define K1PAD 640       // padded K for layer-1 GEMM
#define K2PAD 320       // padded K for layer-2 GEMM
#define MPAD 100096     // 782 * 128

typedef __bf16 bf16;
typedef __bf16 bf16x4 __attribute__((ext_vector_type(4)));
typedef __bf16 bf16x8 __attribute__((ext_vector_type(8)));
typedef float f32x4 __attribute__((ext_vector_type(4)));

__device__ __forceinline__ void gload16(const void* g, void* l) {
    __builtin_amdgcn_global_load_lds(
        (const __attribute__((address_space(1))) unsigned int*)g,
        (__attribute__((address_space(3))) unsigned int*)l, 16, 0, 0);
}

// ---------------- degree counting ----------------
__global__ __launch_bounds__(256) void count_deg(const int* __restrict__ src,
                                                 const int* __restrict__ dst,
                                                 int* __restrict__ deg_out,
                                                 int* __restrict__ deg_in) {
    int e = blockIdx.x * blockDim.x + threadIdx.x;
    if (e < N_EDGES) {
        atomicAdd(&deg_out[src[e]], 1);
        atomicAdd(&deg_in[dst[e]], 1);
    }
}

// ---------------- per-block sums of deg_in ----------------
__global__ __launch_bounds__(256) void block_sum(const int* __restrict__ deg_in,
                                                 int* __restrict__ bsum) {
    __shared__ int s[256];
    int i = blockIdx.x * 256 + threadIdx.x;
    s[threadIdx.x] = (i < N_NODES) ? deg_in[i] : 0;
    __syncthreads();
    for (int off = 128; off; off >>= 1) {
        if (threadIdx.x < off) s[threadIdx.x] += s[threadIdx.x + off];
        __syncthreads();
    }
    if (threadIdx.x == 0) bsum[blockIdx.x] = s[0];
}

// ---------------- serial scan over block sums (tiny) ----------------
__global__ void scan_serial(const int* __restrict__ bsum, int* __restrict__ boff, int nb) {
    if (threadIdx.x == 0 && blockIdx.x == 0) {
        int run = 0;
        for (int i = 0; i < nb; ++i) { boff[i] = run; run += bsum[i]; }
    }
}

// ---------------- per-node CSR offsets + inv-sqrt degrees ----------------
__global__ __launch_bounds__(256) void node_offsets(const int* __restrict__ deg_in,
                                                    const int* __restrict__ deg_out,
                                                    const int* __restrict__ boff,
                                                    int* __restrict__ row_start,
                                                    int* __restrict__ cursor,
                                                    float* __restrict__ inv_in,
                                                    float* __restrict__ inv_out) {
    __shared__ int s[256];
    int i = blockIdx.x * 256 + threadIdx.x;
    int d = (i < N_NODES) ? deg_in[i] : 0;
    s[threadIdx.x] = d;
    __syncthreads();
    for (int off = 1; off < 256; off <<= 1) {
        int v = 0;
        if (threadIdx.x >= off) v = s[threadIdx.x - off];
        __syncthreads();
        if (threadIdx.x >= off) s[threadIdx.x] += v;
        __syncthreads();
    }
    if (i < N_NODES) {
        int excl = s[threadIdx.x] - d;
        int rs = boff[blockIdx.x] + excl;
        row_start[i] = rs;
        cursor[i] = rs;
        int di = deg_in[i];
        int dout = deg_out[i];
        inv_in[i]  = (di   > 0) ? rsqrtf((float)di)   : 0.0f;
        inv_out[i] = (dout > 0) ? rsqrtf((float)dout) : 0.0f;
    }
}

// ---------------- fill CSR adjacency (incoming edges, store src) ----------------
__global__ __launch_bounds__(256) void fill_csr(const int* __restrict__ src,
                                                const int* __restrict__ dst,
                                                int* __restrict__ cursor,
                                                int* __restrict__ adj) {
    int e = blockIdx.x * blockDim.x + threadIdx.x;
    if (e < N_EDGES) {
        int pos = atomicAdd(&cursor[dst[e]], 1);
        adj[pos] = src[e];
    }
}

// ---------------- fp32 -> bf16 conversion of node features, pad K to 640 ----------------
__global__ __launch_bounds__(256) void conv_x(const float* __restrict__ x, bf16* __restrict__ xb) {
    size_t idx = (size_t)blockIdx.x * 256 + threadIdx.x;  // one thread per 8 output cols
    size_t r = idx / (K1PAD / 8);
    int c8 = (int)(idx % (K1PAD / 8)) * 8;
    if (r >= MPAD) return;
    bf16x8 v = {};
    if (r < N_NODES && c8 < D_IN) {  // D_IN = 600 divisible by 8 -> chunks fully in or out
        const float* p = x + r * D_IN + c8;
        float4 f0 = *(const float4*)p;
        float4 f1 = *(const float4*)(p + 4);
        v[0] = (bf16)f0.x; v[1] = (bf16)f0.y; v[2] = (bf16)f0.z; v[3] = (bf16)f0.w;
        v[4] = (bf16)f1.x; v[5] = (bf16)f1.y; v[6] = (bf16)f1.z; v[7] = (bf16)f1.w;
    }
    *(bf16x8*)(xb + r * K1PAD + c8) = v;
}

// ---------------- W [K][N] fp32 -> Bt [NPAD][Kpad] bf16 (transpose + zero pad) ----------------
__global__ __launch_bounds__(256) void conv_bt(const float* __restrict__ W, bf16* __restrict__ Bt,
                                               int K, int N, int Kpad) {
    int idx = blockIdx.x * 256 + threadIdx.x;
    int k = idx % Kpad;
    int n = idx / Kpad;
    if (n >= NPAD) return;
    bf16 v = (bf16)0.0f;
    if (k < K && n < N) v = (bf16)W[(size_t)k * N + n];
    Bt[(size_t)n * Kpad + k] = v;
}

// ---------------- MFMA GEMM: C[r][n] = (sum_k A[r][k] * Bt[n][k]) * rowscale[r] ----------------
// A: [MPAD][Kpad] bf16 row-major; Bt: [NPAD][Kpad] bf16; C: [M][NPAD] bf16.
// 128x64 tile, 4 waves (2x2), 16x16x32 MFMA, XOR-swizzled LDS (T2) staged via
// global_load_lds w/ pre-swizzled source (m201 pattern).
__global__ __launch_bounds__(256) void mfma_gemm(const bf16* __restrict__ A,
                                                 const bf16* __restrict__ Bt,
                                                 const float* __restrict__ rowscale,
                                                 bf16* __restrict__ C,
                                                 int M, int Kpad) {
    __shared__ bf16 As[128 * 64];   // [row][k] 128B/row, slot-swizzled
    __shared__ bf16 Bs[64 * 64];
    const int tid = threadIdx.x;
    const int lane = tid & 63;
    const int wid = tid >> 6;
    const int wr = wid >> 1, wc = wid & 1;
    const int blockRow = blockIdx.y * 128;
    const int blockCol = blockIdx.x * 64;
    const size_t rowBytes = (size_t)Kpad * 2;

    f32x4 acc[4][2] = {};

    const int nK = Kpad >> 6;
    for (int t = 0; t < nK; ++t) {
        const size_t kByte = (size_t)t * 128;
#pragma unroll
        for (int c = 0; c < 4; ++c) {   // A tile: 16 KB
            int o = c * 4096 + tid * 16;
            int row = o >> 7;
            int slot = (o >> 4) & 7;
            int srcs = slot ^ (row & 7);
            const char* g = (const char*)A + (size_t)(blockRow + row) * rowBytes + kByte + srcs * 16;
            gload16(g, (char*)As + o);
        }
#pragma unroll
        for (int c = 0; c < 2; ++c) {   // B tile: 8 KB
            int o = c * 4096 + tid * 16;
            int row = o >> 7;
            int slot = (o >> 4) & 7;
            int srcs = slot ^ (row & 7);
            const char* g = (const char*)Bt + (size_t)(blockCol + row) * rowBytes + kByte + srcs * 16;
            gload16(g, (char*)Bs + o);
        }
        __syncthreads();   // compiler drains vmcnt before s_barrier
#pragma unroll
        for (int kk = 0; kk < 2; ++kk) {
            int slot = kk * 4 + (lane >> 4);
            bf16x8 af[4], bfr[2];
#pragma unroll
            for (int mi = 0; mi < 4; ++mi) {
                int row = wr * 64 + mi * 16 + (lane & 15);
                int addr = row * 128 + ((slot ^ (row & 7)) << 4);
                af[mi] = *(const bf16x8*)((const char*)As + addr);
            }
#pragma unroll
            for (int ni = 0; ni < 2; ++ni) {
                int row = wc * 32 + ni * 16 + (lane & 15);
                int addr = row * 128 + ((slot ^ (row & 7)) << 4);
                bfr[ni] = *(const bf16x8*)((const char*)Bs + addr);
            }
#pragma unroll
            for (int mi = 0; mi < 4; ++mi)
#pragma unroll
                for (int ni = 0; ni < 2; ++ni)
                    acc[mi][ni] = __builtin_amdgcn_mfma_f32_16x16x32_bf16(af[mi], bfr[ni], acc[mi][ni], 0, 0, 0);
        }
        __syncthreads();
    }
    // epilogue: scale by rowscale, convert to bf16, store (cols beyond N are zeros via B padding)
#pragma unroll
    for (int mi = 0; mi < 4; ++mi) {
#pragma unroll
        for (int i = 0; i < 4; ++i) {
            int gr = blockRow + wr * 64 + mi * 16 + ((lane >> 4) << 2) + i;
            if (gr >= M) continue;
            float sc = rowscale[gr];
#pragma unroll
            for (int ni = 0; ni < 2; ++ni) {
                int gc = blockCol + wc * 32 + ni * 16 + (lane & 15);
                C[(size_t)gr * NPAD + gc] = (bf16)(acc[mi][ni][i] * sc);
            }
        }
    }
}

// ---------------- aggregation: h[n] = relu(inv_in[n] * sum m[adj] + bias), bf16 in/out ----------------
__global__ __launch_bounds__(256) void aggregate_bf16(const bf16* __restrict__ m,
                                                      const int* __restrict__ row_start,
                                                      const int* __restrict__ deg_in,
                                                      const int* __restrict__ adj,
                                                      const float* __restrict__ inv_in,
                                                      const float* __restrict__ bias,
                                                      bf16* __restrict__ h) {
    int node = (int)((blockIdx.x * (size_t)blockDim.x + threadIdx.x) >> 6);
    int lane = threadIdx.x & 63;
    if (node >= N_NODES) return;
    int s = row_start[node];
    int d = deg_in[node];
    int cA = lane * 4;          // cols 0..255
    int cB = 256 + lane * 4;    // lanes 0..15 -> cols 256..319
    bool hasB = lane < 16;
    float a0 = 0.f, a1 = 0.f, a2 = 0.f, a3 = 0.f;
    float b0 = 0.f, b1 = 0.f, b2 = 0.f, b3 = 0.f;
    for (int e = 0; e < d; ++e) {
        const bf16* row = m + (size_t)adj[s + e] * NPAD;
        bf16x4 v = *(const bf16x4*)(row + cA);
        a0 += (float)v[0]; a1 += (float)v[1]; a2 += (float)v[2]; a3 += (float)v[3];
        if (hasB) {
            bf16x4 w = *(const bf16x4*)(row + cB);
            b0 += (float)w[0]; b1 += (float)w[1]; b2 += (float)w[2]; b3 += (float)w[3];
        }
    }
    float sc = inv_in[node];
    bf16* out = h + (size_t)node * NPAD;
    bf16x4 o;
    o[0] = (bf16)fmaxf(a0 * sc + bias[cA + 0], 0.f);
    o[1] = (bf16)fmaxf(a1 * sc + bias[cA + 1], 0.f);
    o[2] = (bf16)fmaxf(a2 * sc + bias[cA + 2], 0.f);
    o[3] = (bf16)fmaxf(a3 * sc + bias[cA + 3], 0.f);
    *(bf16x4*)(out + cA) = o;
    if (hasB) {
        float accs[4] = {b0, b1, b2, b3};
        bf16x4 ob;
#pragma unroll
        for (int j = 0; j < 4; ++j) {
            int c = cB + j;
            float val = (c < D_H) ? fmaxf(accs[j] * sc + bias[c], 0.f) : 0.f;
            ob[j] = (bf16)val;
        }
        *(bf16x4*)(out + cB) = ob;
    }
}

// ---------------- fc + softmax + pooled sum (bf16 h) ----------------
__global__ __launch_bounds__(256) void fc_pool(const bf16* __restrict__ h,
                                               const float* __restrict__ Wfc,
                                               const float* __restrict__ bfc,
                                               const int* __restrict__ gid,
                                               float* __restrict__ pooled,
                                               int* __restrict__ gcount) {
    int node = (int)((blockIdx.x * (size_t)blockDim.x + threadIdx.x) >> 6);
    int lane = threadIdx.x & 63;
    if (node >= N_NODES) return;
    const bf16* row = h + (size_t)node * NPAD;
    float a0 = 0.f, a1 = 0.f;
    for (int c = lane; c < D_H; c += 64) {
        float v = (float)row[c];
        a0 += v * Wfc[c * 2];
        a1 += v * Wfc[c * 2 + 1];
    }
    for (int off = 32; off; off >>= 1) {
        a0 += __shfl_down(a0, off);
        a1 += __shfl_down(a1, off);
    }
    if (lane == 0) {
        float z0 = a0 + bfc[0], z1 = a1 + bfc[1];
        float mx = fmaxf(z0, z1);
        float e0 = __expf(z0 - mx), e1 = __expf(z1 - mx);
        float inv = 1.f / (e0 + e1);
        int g = gid[node];
        atomicAdd(&pooled[g * 2 + 0], e0 * inv);
        atomicAdd(&pooled[g * 2 + 1], e1 * inv);
        atomicAdd(&gcount[g], 1);
    }
}

// ---------------- finalize: divide by counts ----------------
__global__ __launch_bounds__(256) void finalize(const float* __restrict__ pooled,
                                                const int* __restrict__ gcount,
                                                float* __restrict__ out) {
    int i = blockIdx.x * blockDim.x + threadIdx.x;
    if (i < N_GRAPHS * 2) {
        int g = i >> 1;
        float c = (float)max(gcount[g], 1);
        out[i] = pooled[i] / c;
    }
}

extern "C" void kernel_launch(void* const* d_in, const int* in_sizes, int n_in,
                              void* d_out, int out_size, void* d_ws, size_t ws_size,
                              hipStream_t stream) {
    const float* x   = (const float*)d_in[0];
    const float* W1  = (const float*)d_in[1];
    const float* b1  = (const float*)d_in[2];
    const float* W2  = (const float*)d_in[3];
    const float* b2  = (const float*)d_in[4];
    const float* Wfc = (const float*)d_in[5];
    const float* bfc = (const float*)d_in[6];
    const int* src   = (const int*)d_in[7];
    const int* dst   = (const int*)d_in[8];
    const int* gid   = (const int*)d_in[9];

    char* ws = (char*)d_ws;
    size_t off = 0;
    auto alloc = [&](size_t bytes) -> void* {
        void* p = ws + off;
        off = (off + bytes + 255) & ~(size_t)255;
        return p;
    };
    bf16* x_bf   = (bf16*)alloc((size_t)MPAD * K1PAD * 2);     // 128.1 MB
    bf16* h_bf   = (bf16*)alloc((size_t)MPAD * NPAD * 2);      // 64.1 MB
    bf16* m_bf   = (bf16*)alloc((size_t)N_NODES * NPAD * 2);   // 64.0 MB
    bf16* B1t    = (bf16*)alloc((size_t)NPAD * K1PAD * 2);     // 0.4 MB
    bf16* B2t    = (bf16*)alloc((size_t)NPAD * K2PAD * 2);     // 0.2 MB
    int*   adj      = (int*)alloc((size_t)N_EDGES * 4);
    int*   row_st   = (int*)alloc((size_t)N_NODES * 4);
    int*   cursor   = (int*)alloc((size_t)N_NODES * 4);
    int*   deg_in   = (int*)alloc((size_t)N_NODES * 4);
    int*   deg_out  = (int*)alloc((size_t)N_NODES * 4);
    float* inv_in   = (float*)alloc((size_t)N_NODES * 4);
    float* inv_out  = (float*)alloc((size_t)N_NODES * 4);
    const int NB = (N_NODES + 255) / 256;
    int*   bsum     = (int*)alloc((size_t)NB * 4);
    int*   boff     = (int*)alloc((size_t)NB * 4);
    float* pooled   = (float*)alloc((size_t)N_GRAPHS * 2 * 4);
    int*   gcount   = (int*)alloc((size_t)N_GRAPHS * 4);

    hipMemsetAsync(deg_in, 0, (size_t)N_NODES * 4, stream);
    hipMemsetAsync(deg_out, 0, (size_t)N_NODES * 4, stream);
    hipMemsetAsync(pooled, 0, (size_t)N_GRAPHS * 2 * 4, stream);
    hipMemsetAsync(gcount, 0, (size_t)N_GRAPHS * 4, stream);

    // graph preprocessing
    count_deg<<<(N_EDGES + 255) / 256, 256, 0, stream>>>(src, dst, deg_out, deg_in);
    block_sum<<<NB, 256, 0, stream>>>(deg_in, bsum);
    scan_serial<<<1, 64, 0, stream>>>(bsum, boff, NB);
    node_offsets<<<NB, 256, 0, stream>>>(deg_in, deg_out, boff, row_st, cursor, inv_in, inv_out);
    fill_csr<<<(N_EDGES + 255) / 256, 256, 0, stream>>>(src, dst, cursor, adj);

    // bf16 conversions
    conv_x<<<(MPAD * (K1PAD / 8) + 255) / 256, 256, 0, stream>>>(x, x_bf);
    conv_bt<<<(NPAD * K1PAD + 255) / 256, 256, 0, stream>>>(W1, B1t, D_IN, D_H, K1PAD);
    conv_bt<<<(NPAD * K2PAD + 255) / 256, 256, 0, stream>>>(W2, B2t, D_H, D_H, K2PAD);

    dim3 ggrid(NPAD / 64, MPAD / 128);
    // layer 1
    mfma_gemm<<<ggrid, 256, 0, stream>>>(x_bf, B1t, inv_out, m_bf, N_NODES, K1PAD);
    aggregate_bf16<<<(N_NODES * 64 + 255) / 256, 256, 0, stream>>>(m_bf, row_st, deg_in, adj, inv_in, b1, h_bf);
    // layer 2
    mfma_gemm<<<ggrid, 256, 0, stream>>>(h_bf, B2t, inv_out, m_bf, N_NODES, K2PAD);
    aggregate_bf16<<<(N_NODES * 64 + 255) / 256, 256, 0, stream>>>(m_bf, row_st, deg_in, adj, inv_in, b2, h_bf);
    // head
    fc_pool<<<(N_NODES * 64 + 255) / 256, 256, 0, stream>>>(h_bf, Wfc, bfc, gid, pooled, gcount);
    finalize<<<(N_GRAPHS * 2 + 255) / 256, 256, 0, stream>>>(pooled, gcount, (float*)d_out);
}

// Round 3
// 832.559 us; speedup vs baseline: 2.1470x; 1.2348x over previous
//
#include <hip/hip_runtime.h>
#include <hip/hip_bf16.h>

#define N_NODES 100000
#define N_EDGES 1600000
#define N_GRAPHS 2000
#define D_IN 600
#define D_H 300
#define D_OUT 2

#define NPAD 320        // padded hidden width (multiple of 64)
#define K1PAD 640       // padded K for layer-1 GEMM
#define K2PAD 320       // padded K for layer-2 GEMM
#define MPAD 100096     // 782 * 128

typedef __bf16 bf16;
typedef __bf16 bf16x4 __attribute__((ext_vector_type(4)));
typedef __bf16 bf16x8 __attribute__((ext_vector_type(8)));
typedef float f32x4 __attribute__((ext_vector_type(4)));

__device__ __forceinline__ void gload16(const void* g, void* l) {
    __builtin_amdgcn_global_load_lds(
        (const __attribute__((address_space(1))) unsigned int*)g,
        (__attribute__((address_space(3))) unsigned int*)l, 16, 0, 0);
}

// ---------------- degree counting ----------------
__global__ __launch_bounds__(256) void count_deg(const int* __restrict__ src,
                                                 const int* __restrict__ dst,
                                                 int* __restrict__ deg_out,
                                                 int* __restrict__ deg_in) {
    int e = blockIdx.x * blockDim.x + threadIdx.x;
    if (e < N_EDGES) {
        atomicAdd(&deg_out[src[e]], 1);
        atomicAdd(&deg_in[dst[e]], 1);
    }
}

// ---------------- per-block sums of deg_in ----------------
__global__ __launch_bounds__(256) void block_sum(const int* __restrict__ deg_in,
                                                 int* __restrict__ bsum) {
    __shared__ int s[256];
    int i = blockIdx.x * 256 + threadIdx.x;
    s[threadIdx.x] = (i < N_NODES) ? deg_in[i] : 0;
    __syncthreads();
    for (int off = 128; off; off >>= 1) {
        if (threadIdx.x < off) s[threadIdx.x] += s[threadIdx.x + off];
        __syncthreads();
    }
    if (threadIdx.x == 0) bsum[blockIdx.x] = s[0];
}

// ---------------- serial scan over block sums (tiny) ----------------
__global__ void scan_serial(const int* __restrict__ bsum, int* __restrict__ boff, int nb) {
    if (threadIdx.x == 0 && blockIdx.x == 0) {
        int run = 0;
        for (int i = 0; i < nb; ++i) { boff[i] = run; run += bsum[i]; }
    }
}

// ---------------- per-node CSR offsets + inv-sqrt degrees ----------------
__global__ __launch_bounds__(256) void node_offsets(const int* __restrict__ deg_in,
                                                    const int* __restrict__ deg_out,
                                                    const int* __restrict__ boff,
                                                    int* __restrict__ row_start,
                                                    int* __restrict__ cursor,
                                                    float* __restrict__ inv_in,
                                                    float* __restrict__ inv_out) {
    __shared__ int s[256];
    int i = blockIdx.x * 256 + threadIdx.x;
    int d = (i < N_NODES) ? deg_in[i] : 0;
    s[threadIdx.x] = d;
    __syncthreads();
    for (int off = 1; off < 256; off <<= 1) {
        int v = 0;
        if (threadIdx.x >= off) v = s[threadIdx.x - off];
        __syncthreads();
        if (threadIdx.x >= off) s[threadIdx.x] += v;
        __syncthreads();
    }
    if (i < N_NODES) {
        int excl = s[threadIdx.x] - d;
        int rs = boff[blockIdx.x] + excl;
        row_start[i] = rs;
        cursor[i] = rs;
        int di = deg_in[i];
        int dout = deg_out[i];
        inv_in[i]  = (di   > 0) ? rsqrtf((float)di)   : 0.0f;
        inv_out[i] = (dout > 0) ? rsqrtf((float)dout) : 0.0f;
    }
}

// ---------------- fill CSR adjacency (incoming edges, store src) ----------------
__global__ __launch_bounds__(256) void fill_csr(const int* __restrict__ src,
                                                const int* __restrict__ dst,
                                                int* __restrict__ cursor,
                                                int* __restrict__ adj) {
    int e = blockIdx.x * blockDim.x + threadIdx.x;
    if (e < N_EDGES) {
        int pos = atomicAdd(&cursor[dst[e]], 1);
        adj[pos] = src[e];
    }
}

// ---------------- fp32 -> bf16 conversion of node features, pad K to 640 ----------------
__global__ __launch_bounds__(256) void conv_x(const float* __restrict__ x, bf16* __restrict__ xb) {
    size_t idx = (size_t)blockIdx.x * 256 + threadIdx.x;  // one thread per 8 output cols
    size_t r = idx / (K1PAD / 8);
    int c8 = (int)(idx % (K1PAD / 8)) * 8;
    if (r >= MPAD) return;
    bf16x8 v = {};
    if (r < N_NODES && c8 < D_IN) {  // D_IN = 600 divisible by 8 -> chunks fully in or out
        const float* p = x + r * D_IN + c8;
        float4 f0 = *(const float4*)p;
        float4 f1 = *(const float4*)(p + 4);
        v[0] = (bf16)f0.x; v[1] = (bf16)f0.y; v[2] = (bf16)f0.z; v[3] = (bf16)f0.w;
        v[4] = (bf16)f1.x; v[5] = (bf16)f1.y; v[6] = (bf16)f1.z; v[7] = (bf16)f1.w;
    }
    *(bf16x8*)(xb + r * K1PAD + c8) = v;
}

// ---------------- W [K][N] fp32 -> Bt [NPAD][Kpad] bf16 (transpose + zero pad) ----------------
__global__ __launch_bounds__(256) void conv_bt(const float* __restrict__ W, bf16* __restrict__ Bt,
                                               int K, int N, int Kpad) {
    int idx = blockIdx.x * 256 + threadIdx.x;
    int k = idx % Kpad;
    int n = idx / Kpad;
    if (n >= NPAD) return;
    bf16 v = (bf16)0.0f;
    if (k < K && n < N) v = (bf16)W[(size_t)k * N + n];
    Bt[(size_t)n * Kpad + k] = v;
}

// ---------------- MFMA GEMM: C[r][n] = (sum_k A[r][k] * Bt[n][k]) * rowscale[r] ----------------
__global__ __launch_bounds__(256) void mfma_gemm(const bf16* __restrict__ A,
                                                 const bf16* __restrict__ Bt,
                                                 const float* __restrict__ rowscale,
                                                 bf16* __restrict__ C,
                                                 int M, int Kpad) {
    __shared__ bf16 As[128 * 64];   // [row][k] 128B/row, slot-swizzled
    __shared__ bf16 Bs[64 * 64];
    const int tid = threadIdx.x;
    const int lane = tid & 63;
    const int wid = tid >> 6;
    const int wr = wid >> 1, wc = wid & 1;
    const int blockRow = blockIdx.y * 128;
    const int blockCol = blockIdx.x * 64;
    const size_t rowBytes = (size_t)Kpad * 2;

    f32x4 acc[4][2] = {};

    const int nK = Kpad >> 6;
    for (int t = 0; t < nK; ++t) {
        const size_t kByte = (size_t)t * 128;
#pragma unroll
        for (int c = 0; c < 4; ++c) {   // A tile: 16 KB
            int o = c * 4096 + tid * 16;
            int row = o >> 7;
            int slot = (o >> 4) & 7;
            int srcs = slot ^ (row & 7);
            const char* g = (const char*)A + (size_t)(blockRow + row) * rowBytes + kByte + srcs * 16;
            gload16(g, (char*)As + o);
        }
#pragma unroll
        for (int c = 0; c < 2; ++c) {   // B tile: 8 KB
            int o = c * 4096 + tid * 16;
            int row = o >> 7;
            int slot = (o >> 4) & 7;
            int srcs = slot ^ (row & 7);
            const char* g = (const char*)Bt + (size_t)(blockCol + row) * rowBytes + kByte + srcs * 16;
            gload16(g, (char*)Bs + o);
        }
        __syncthreads();
#pragma unroll
        for (int kk = 0; kk < 2; ++kk) {
            int slot = kk * 4 + (lane >> 4);
            bf16x8 af[4], bfr[2];
#pragma unroll
            for (int mi = 0; mi < 4; ++mi) {
                int row = wr * 64 + mi * 16 + (lane & 15);
                int addr = row * 128 + ((slot ^ (row & 7)) << 4);
                af[mi] = *(const bf16x8*)((const char*)As + addr);
            }
#pragma unroll
            for (int ni = 0; ni < 2; ++ni) {
                int row = wc * 32 + ni * 16 + (lane & 15);
                int addr = row * 128 + ((slot ^ (row & 7)) << 4);
                bfr[ni] = *(const bf16x8*)((const char*)Bs + addr);
            }
#pragma unroll
            for (int mi = 0; mi < 4; ++mi)
#pragma unroll
                for (int ni = 0; ni < 2; ++ni)
                    acc[mi][ni] = __builtin_amdgcn_mfma_f32_16x16x32_bf16(af[mi], bfr[ni], acc[mi][ni], 0, 0, 0);
        }
        __syncthreads();
    }
#pragma unroll
    for (int mi = 0; mi < 4; ++mi) {
#pragma unroll
        for (int i = 0; i < 4; ++i) {
            int gr = blockRow + wr * 64 + mi * 16 + ((lane >> 4) << 2) + i;
            if (gr >= M) continue;
            float sc = rowscale[gr];
#pragma unroll
            for (int ni = 0; ni < 2; ++ni) {
                int gc = blockCol + wc * 32 + ni * 16 + (lane & 15);
                C[(size_t)gr * NPAD + gc] = (bf16)(acc[mi][ni][i] * sc);
            }
        }
    }
}

// ---------------- gather accumulate core: 5 cols per lane (lane*4 .. +3, 256+lane) ----------------
// Unrolled x4 for memory-level parallelism (4 independent row gathers in flight).
__device__ __forceinline__ void gather_rows(const bf16* __restrict__ m,
                                            const int* __restrict__ adj,
                                            int s, int d, int cA, int c4,
                                            float acc[5]) {
    int e = 0;
    for (; e + 4 <= d; e += 4) {
        int i0 = adj[s + e], i1 = adj[s + e + 1], i2 = adj[s + e + 2], i3 = adj[s + e + 3];
        const bf16* r0 = m + (size_t)i0 * NPAD;
        const bf16* r1 = m + (size_t)i1 * NPAD;
        const bf16* r2 = m + (size_t)i2 * NPAD;
        const bf16* r3 = m + (size_t)i3 * NPAD;
        bf16x4 v0 = *(const bf16x4*)(r0 + cA);
        bf16x4 v1 = *(const bf16x4*)(r1 + cA);
        bf16x4 v2 = *(const bf16x4*)(r2 + cA);
        bf16x4 v3 = *(const bf16x4*)(r3 + cA);
        bf16 w0 = r0[c4], w1 = r1[c4], w2 = r2[c4], w3 = r3[c4];
        acc[0] += (float)v0[0] + (float)v1[0] + (float)v2[0] + (float)v3[0];
        acc[1] += (float)v0[1] + (float)v1[1] + (float)v2[1] + (float)v3[1];
        acc[2] += (float)v0[2] + (float)v1[2] + (float)v2[2] + (float)v3[2];
        acc[3] += (float)v0[3] + (float)v1[3] + (float)v2[3] + (float)v3[3];
        acc[4] += (float)w0 + (float)w1 + (float)w2 + (float)w3;
    }
    for (; e < d; ++e) {
        const bf16* r = m + (size_t)adj[s + e] * NPAD;
        bf16x4 v = *(const bf16x4*)(r + cA);
        acc[0] += (float)v[0];
        acc[1] += (float)v[1];
        acc[2] += (float)v[2];
        acc[3] += (float)v[3];
        acc[4] += (float)r[c4];
    }
}

// ---------------- layer-1 aggregation: h = relu(inv_in * sum m[adj] + bias) ----------------
__global__ __launch_bounds__(256) void aggregate_bf16(const bf16* __restrict__ m,
                                                      const int* __restrict__ row_start,
                                                      const int* __restrict__ deg_in,
                                                      const int* __restrict__ adj,
                                                      const float* __restrict__ inv_in,
                                                      const float* __restrict__ bias,
                                                      bf16* __restrict__ h) {
    int node = (int)((blockIdx.x * (size_t)blockDim.x + threadIdx.x) >> 6);
    int lane = threadIdx.x & 63;
    if (node >= N_NODES) return;
    int s = row_start[node];
    int d = deg_in[node];
    int cA = lane * 4;
    int c4 = 256 + lane;
    float acc[5] = {};
    gather_rows(m, adj, s, d, cA, c4, acc);
    float sc = inv_in[node];
    bf16* out = h + (size_t)node * NPAD;
    bf16x4 o;
    o[0] = (bf16)fmaxf(acc[0] * sc + bias[cA + 0], 0.f);
    o[1] = (bf16)fmaxf(acc[1] * sc + bias[cA + 1], 0.f);
    o[2] = (bf16)fmaxf(acc[2] * sc + bias[cA + 2], 0.f);
    o[3] = (bf16)fmaxf(acc[3] * sc + bias[cA + 3], 0.f);
    *(bf16x4*)(out + cA) = o;
    float v4 = (c4 < D_H) ? fmaxf(acc[4] * sc + bias[c4], 0.f) : 0.f;
    out[c4] = (bf16)v4;
}

// ---------------- fused layer-2 aggregation + fc + softmax + pooling ----------------
__global__ __launch_bounds__(256) void agg2_fc_pool(const bf16* __restrict__ m,
                                                    const int* __restrict__ row_start,
                                                    const int* __restrict__ deg_in,
                                                    const int* __restrict__ adj,
                                                    const float* __restrict__ inv_in,
                                                    const float* __restrict__ bias,
                                                    const float* __restrict__ Wfc,
                                                    const float* __restrict__ bfc,
                                                    const int* __restrict__ gid,
                                                    float* __restrict__ pooled,
                                                    int* __restrict__ gcount) {
    int node = (int)((blockIdx.x * (size_t)blockDim.x + threadIdx.x) >> 6);
    int lane = threadIdx.x & 63;
    if (node >= N_NODES) return;
    int s = row_start[node];
    int d = deg_in[node];
    int cA = lane * 4;
    int c4 = 256 + lane;
    float acc[5] = {};
    gather_rows(m, adj, s, d, cA, c4, acc);
    float sc = inv_in[node];
    // h columns in registers
    float h0 = fmaxf(acc[0] * sc + bias[cA + 0], 0.f);
    float h1 = fmaxf(acc[1] * sc + bias[cA + 1], 0.f);
    float h2 = fmaxf(acc[2] * sc + bias[cA + 2], 0.f);
    float h3 = fmaxf(acc[3] * sc + bias[cA + 3], 0.f);
    float h4 = (c4 < D_H) ? fmaxf(acc[4] * sc + bias[c4], 0.f) : 0.f;
    // fc dot: Wfc is [D_H][2] row-major -> 8 consecutive floats at cA*2
    float4 wA0 = *(const float4*)(Wfc + cA * 2);       // c=cA, cA+1 (interleaved)
    float4 wA1 = *(const float4*)(Wfc + cA * 2 + 4);   // c=cA+2, cA+3
    float z0 = h0 * wA0.x + h1 * wA0.z + h2 * wA1.x + h3 * wA1.z;
    float z1 = h0 * wA0.y + h1 * wA0.w + h2 * wA1.y + h3 * wA1.w;
    if (c4 < D_H) {
        z0 += h4 * Wfc[c4 * 2];
        z1 += h4 * Wfc[c4 * 2 + 1];
    }
    for (int off = 32; off; off >>= 1) {
        z0 += __shfl_down(z0, off);
        z1 += __shfl_down(z1, off);
    }
    if (lane == 0) {
        float s0 = z0 + bfc[0], s1 = z1 + bfc[1];
        float mx = fmaxf(s0, s1);
        float e0 = __expf(s0 - mx), e1 = __expf(s1 - mx);
        float inv = 1.f / (e0 + e1);
        int g = gid[node];
        atomicAdd(&pooled[g * 2 + 0], e0 * inv);
        atomicAdd(&pooled[g * 2 + 1], e1 * inv);
        atomicAdd(&gcount[g], 1);
    }
}

// ---------------- finalize: divide by counts ----------------
__global__ __launch_bounds__(256) void finalize(const float* __restrict__ pooled,
                                                const int* __restrict__ gcount,
                                                float* __restrict__ out) {
    int i = blockIdx.x * blockDim.x + threadIdx.x;
    if (i < N_GRAPHS * 2) {
        int g = i >> 1;
        float c = (float)max(gcount[g], 1);
        out[i] = pooled[i] / c;
    }
}

extern "C" void kernel_launch(void* const* d_in, const int* in_sizes, int n_in,
                              void* d_out, int out_size, void* d_ws, size_t ws_size,
                              hipStream_t stream) {
    const float* x   = (const float*)d_in[0];
    const float* W1  = (const float*)d_in[1];
    const float* b1  = (const float*)d_in[2];
    const float* W2  = (const float*)d_in[3];
    const float* b2  = (const float*)d_in[4];
    const float* Wfc = (const float*)d_in[5];
    const float* bfc = (const float*)d_in[6];
    const int* src   = (const int*)d_in[7];
    const int* dst   = (const int*)d_in[8];
    const int* gid   = (const int*)d_in[9];

    char* ws = (char*)d_ws;
    size_t off = 0;
    auto alloc = [&](size_t bytes) -> void* {
        void* p = ws + off;
        off = (off + bytes + 255) & ~(size_t)255;
        return p;
    };
    bf16* x_bf   = (bf16*)alloc((size_t)MPAD * K1PAD * 2);     // 128.1 MB
    bf16* h_bf   = (bf16*)alloc((size_t)MPAD * NPAD * 2);      // 64.1 MB
    bf16* m_bf   = (bf16*)alloc((size_t)N_NODES * NPAD * 2);   // 64.0 MB
    bf16* B1t    = (bf16*)alloc((size_t)NPAD * K1PAD * 2);     // 0.4 MB
    bf16* B2t    = (bf16*)alloc((size_t)NPAD * K2PAD * 2);     // 0.2 MB
    int*   adj      = (int*)alloc((size_t)N_EDGES * 4);
    int*   row_st   = (int*)alloc((size_t)N_NODES * 4);
    int*   cursor   = (int*)alloc((size_t)N_NODES * 4);
    int*   deg_in   = (int*)alloc((size_t)N_NODES * 4);
    int*   deg_out  = (int*)alloc((size_t)N_NODES * 4);
    float* inv_in   = (float*)alloc((size_t)N_NODES * 4);
    float* inv_out  = (float*)alloc((size_t)N_NODES * 4);
    const int NB = (N_NODES + 255) / 256;
    int*   bsum     = (int*)alloc((size_t)NB * 4);
    int*   boff     = (int*)alloc((size_t)NB * 4);
    float* pooled   = (float*)alloc((size_t)N_GRAPHS * 2 * 4);
    int*   gcount   = (int*)alloc((size_t)N_GRAPHS * 4);

    hipMemsetAsync(deg_in, 0, (size_t)N_NODES * 4, stream);
    hipMemsetAsync(deg_out, 0, (size_t)N_NODES * 4, stream);
    hipMemsetAsync(pooled, 0, (size_t)N_GRAPHS * 2 * 4, stream);
    hipMemsetAsync(gcount, 0, (size_t)N_GRAPHS * 4, stream);

    // graph preprocessing
    count_deg<<<(N_EDGES + 255) / 256, 256, 0, stream>>>(src, dst, deg_out, deg_in);
    block_sum<<<NB, 256, 0, stream>>>(deg_in, bsum);
    scan_serial<<<1, 64, 0, stream>>>(bsum, boff, NB);
    node_offsets<<<NB, 256, 0, stream>>>(deg_in, deg_out, boff, row_st, cursor, inv_in, inv_out);
    fill_csr<<<(N_EDGES + 255) / 256, 256, 0, stream>>>(src, dst, cursor, adj);

    // bf16 conversions
    conv_x<<<(MPAD * (K1PAD / 8) + 255) / 256, 256, 0, stream>>>(x, x_bf);
    conv_bt<<<(NPAD * K1PAD + 255) / 256, 256, 0, stream>>>(W1, B1t, D_IN, D_H, K1PAD);
    conv_bt<<<(NPAD * K2PAD + 255) / 256, 256, 0, stream>>>(W2, B2t, D_H, D_H, K2PAD);

    dim3 ggrid(NPAD / 64, MPAD / 128);
    // layer 1
    mfma_gemm<<<ggrid, 256, 0, stream>>>(x_bf, B1t, inv_out, m_bf, N_NODES, K1PAD);
    aggregate_bf16<<<(N_NODES * 64 + 255) / 256, 256, 0, stream>>>(m_bf, row_st, deg_in, adj, inv_in, b1, h_bf);
    // layer 2
    mfma_gemm<<<ggrid, 256, 0, stream>>>(h_bf, B2t, inv_out, m_bf, N_NODES, K2PAD);
    // fused layer-2 aggregate + fc + softmax + pooling
    agg2_fc_pool<<<(N_NODES * 64 + 255) / 256, 256, 0, stream>>>(m_bf, row_st, deg_in, adj, inv_in, b2,
                                                                 Wfc, bfc, gid, pooled, gcount);
    finalize<<<(N_GRAPHS * 2 + 255) / 256, 256, 0, stream>>>(pooled, gcount, (float*)d_out);
}

// Round 4
// 827.840 us; speedup vs baseline: 2.1592x; 1.0057x over previous
//
#include <hip/hip_runtime.h>
#include <hip/hip_bf16.h>

#define N_NODES 100000
#define N_EDGES 1600000
#define N_GRAPHS 2000
#define D_IN 600
#define D_H 300
#define D_OUT 2

#define NPAD 320        // padded hidden width (multiple of 64)
#define K1PAD 640       // padded K for layer-1 GEMM
#define K2PAD 320       // padded K for layer-2 GEMM
#define MPAD 100096     // 782 * 128

typedef __bf16 bf16;
typedef __bf16 bf16x8 __attribute__((ext_vector_type(8)));
typedef float f32x4 __attribute__((ext_vector_type(4)));

__device__ __forceinline__ void gload16(const void* g, void* l) {
    __builtin_amdgcn_global_load_lds(
        (const __attribute__((address_space(1))) unsigned int*)g,
        (__attribute__((address_space(3))) unsigned int*)l, 16, 0, 0);
}

// ---------------- degree counting ----------------
__global__ __launch_bounds__(256) void count_deg(const int* __restrict__ src,
                                                 const int* __restrict__ dst,
                                                 int* __restrict__ deg_out,
                                                 int* __restrict__ deg_in) {
    int e = blockIdx.x * blockDim.x + threadIdx.x;
    if (e < N_EDGES) {
        atomicAdd(&deg_out[src[e]], 1);
        atomicAdd(&deg_in[dst[e]], 1);
    }
}

// ---------------- per-block sums of deg_in ----------------
__global__ __launch_bounds__(256) void block_sum(const int* __restrict__ deg_in,
                                                 int* __restrict__ bsum) {
    __shared__ int s[256];
    int i = blockIdx.x * 256 + threadIdx.x;
    s[threadIdx.x] = (i < N_NODES) ? deg_in[i] : 0;
    __syncthreads();
    for (int off = 128; off; off >>= 1) {
        if (threadIdx.x < off) s[threadIdx.x] += s[threadIdx.x + off];
        __syncthreads();
    }
    if (threadIdx.x == 0) bsum[blockIdx.x] = s[0];
}

// ---------------- serial scan over block sums (tiny) ----------------
__global__ void scan_serial(const int* __restrict__ bsum, int* __restrict__ boff, int nb) {
    if (threadIdx.x == 0 && blockIdx.x == 0) {
        int run = 0;
        for (int i = 0; i < nb; ++i) { boff[i] = run; run += bsum[i]; }
    }
}

// ---------------- per-node CSR offsets + inv-sqrt degrees ----------------
__global__ __launch_bounds__(256) void node_offsets(const int* __restrict__ deg_in,
                                                    const int* __restrict__ deg_out,
                                                    const int* __restrict__ boff,
                                                    int* __restrict__ row_start,
                                                    int* __restrict__ cursor,
                                                    float* __restrict__ inv_in,
                                                    float* __restrict__ inv_out) {
    __shared__ int s[256];
    int i = blockIdx.x * 256 + threadIdx.x;
    int d = (i < N_NODES) ? deg_in[i] : 0;
    s[threadIdx.x] = d;
    __syncthreads();
    for (int off = 1; off < 256; off <<= 1) {
        int v = 0;
        if (threadIdx.x >= off) v = s[threadIdx.x - off];
        __syncthreads();
        if (threadIdx.x >= off) s[threadIdx.x] += v;
        __syncthreads();
    }
    if (i < N_NODES) {
        int excl = s[threadIdx.x] - d;
        int rs = boff[blockIdx.x] + excl;
        row_start[i] = rs;
        cursor[i] = rs;
        int di = deg_in[i];
        int dout = deg_out[i];
        inv_in[i]  = (di   > 0) ? rsqrtf((float)di)   : 0.0f;
        inv_out[i] = (dout > 0) ? rsqrtf((float)dout) : 0.0f;
    }
}

// ---------------- fill CSR adjacency (incoming edges, store src) ----------------
__global__ __launch_bounds__(256) void fill_csr(const int* __restrict__ src,
                                                const int* __restrict__ dst,
                                                int* __restrict__ cursor,
                                                int* __restrict__ adj) {
    int e = blockIdx.x * blockDim.x + threadIdx.x;
    if (e < N_EDGES) {
        int pos = atomicAdd(&cursor[dst[e]], 1);
        adj[pos] = src[e];
    }
}

// ---------------- fp32 -> bf16 conversion of node features, pad K to 640 ----------------
__global__ __launch_bounds__(256) void conv_x(const float* __restrict__ x, bf16* __restrict__ xb) {
    size_t idx = (size_t)blockIdx.x * 256 + threadIdx.x;
    size_t r = idx / (K1PAD / 8);
    int c8 = (int)(idx % (K1PAD / 8)) * 8;
    if (r >= MPAD) return;
    bf16x8 v = {};
    if (r < N_NODES && c8 < D_IN) {
        const float* p = x + r * D_IN + c8;
        float4 f0 = *(const float4*)p;
        float4 f1 = *(const float4*)(p + 4);
        v[0] = (bf16)f0.x; v[1] = (bf16)f0.y; v[2] = (bf16)f0.z; v[3] = (bf16)f0.w;
        v[4] = (bf16)f1.x; v[5] = (bf16)f1.y; v[6] = (bf16)f1.z; v[7] = (bf16)f1.w;
    }
    *(bf16x8*)(xb + r * K1PAD + c8) = v;
}

// ---------------- W [K][N] fp32 -> Bt [NPAD][Kpad] bf16 (transpose + zero pad) ----------------
__global__ __launch_bounds__(256) void conv_bt(const float* __restrict__ W, bf16* __restrict__ Bt,
                                               int K, int N, int Kpad) {
    int idx = blockIdx.x * 256 + threadIdx.x;
    int k = idx % Kpad;
    int n = idx / Kpad;
    if (n >= NPAD) return;
    bf16 v = (bf16)0.0f;
    if (k < K && n < N) v = (bf16)W[(size_t)k * N + n];
    Bt[(size_t)n * Kpad + k] = v;
}

// ---------------- pad bias / Wfc to NPAD with zeros ----------------
__global__ __launch_bounds__(256) void prep_small(const float* __restrict__ b1,
                                                  const float* __restrict__ b2,
                                                  const float* __restrict__ Wfc,
                                                  float* __restrict__ b1p,
                                                  float* __restrict__ b2p,
                                                  float* __restrict__ wfcp) {
    int i = blockIdx.x * 256 + threadIdx.x;
    if (i < NPAD) {
        b1p[i] = (i < D_H) ? b1[i] : 0.f;
        b2p[i] = (i < D_H) ? b2[i] : 0.f;
    }
    if (i < NPAD * 2) {
        wfcp[i] = (i < D_H * 2) ? Wfc[i] : 0.f;
    }
}

// ---------------- MFMA GEMM, BN=320 (full N per block): A read once ----------------
// A: [MPAD][Kpad] bf16; Bt: [NPAD][Kpad] bf16; C: [*][NPAD] bf16 = (A·Bt^T)*rowscale.
// 128x320 tile, 8 waves (2x4), 16x16x32 MFMA, XOR-swizzled LDS staged via
// global_load_lds with pre-swizzled source.
__global__ __launch_bounds__(512) void mfma_gemm(const bf16* __restrict__ A,
                                                 const bf16* __restrict__ Bt,
                                                 const float* __restrict__ rowscale,
                                                 bf16* __restrict__ C,
                                                 int M, int Kpad) {
    __shared__ bf16 As[128 * 64];   // 16 KB
    __shared__ bf16 Bs[320 * 64];   // 40 KB
    const int tid = threadIdx.x;
    const int lane = tid & 63;
    const int wid = tid >> 6;       // 0..7
    const int wr = wid >> 2;        // 0..1 -> 64-row half
    const int wc = wid & 3;         // 0..3 -> 80-col quarter
    const int blockRow = blockIdx.x * 128;
    const size_t rowBytes = (size_t)Kpad * 2;

    f32x4 acc[4][5] = {};

    const int nK = Kpad >> 6;
    for (int t = 0; t < nK; ++t) {
        const size_t kByte = (size_t)t * 128;
#pragma unroll
        for (int c = 0; c < 2; ++c) {   // A tile: 16 KB (512 thr x 16 B x 2)
            int o = c * 8192 + tid * 16;
            int row = o >> 7;
            int slot = (o >> 4) & 7;
            int srcs = slot ^ (row & 7);
            const char* g = (const char*)A + (size_t)(blockRow + row) * rowBytes + kByte + srcs * 16;
            gload16(g, (char*)As + o);
        }
#pragma unroll
        for (int c = 0; c < 5; ++c) {   // B tile: 40 KB
            int o = c * 8192 + tid * 16;
            int row = o >> 7;
            int slot = (o >> 4) & 7;
            int srcs = slot ^ (row & 7);
            const char* g = (const char*)Bt + (size_t)row * rowBytes + kByte + srcs * 16;
            gload16(g, (char*)Bs + o);
        }
        __syncthreads();
#pragma unroll
        for (int kk = 0; kk < 2; ++kk) {
            int slot = kk * 4 + (lane >> 4);
            bf16x8 af[4], bfr[5];
#pragma unroll
            for (int mi = 0; mi < 4; ++mi) {
                int row = wr * 64 + mi * 16 + (lane & 15);
                int addr = row * 128 + ((slot ^ (row & 7)) << 4);
                af[mi] = *(const bf16x8*)((const char*)As + addr);
            }
#pragma unroll
            for (int ni = 0; ni < 5; ++ni) {
                int row = wc * 80 + ni * 16 + (lane & 15);
                int addr = row * 128 + ((slot ^ (row & 7)) << 4);
                bfr[ni] = *(const bf16x8*)((const char*)Bs + addr);
            }
#pragma unroll
            for (int mi = 0; mi < 4; ++mi)
#pragma unroll
                for (int ni = 0; ni < 5; ++ni)
                    acc[mi][ni] = __builtin_amdgcn_mfma_f32_16x16x32_bf16(af[mi], bfr[ni], acc[mi][ni], 0, 0, 0);
        }
        __syncthreads();
    }
#pragma unroll
    for (int mi = 0; mi < 4; ++mi) {
#pragma unroll
        for (int i = 0; i < 4; ++i) {
            int gr = blockRow + wr * 64 + mi * 16 + ((lane >> 4) << 2) + i;
            if (gr >= M) continue;
            float sc = rowscale[gr];
#pragma unroll
            for (int ni = 0; ni < 5; ++ni) {
                int gc = wc * 80 + ni * 16 + (lane & 15);
                C[(size_t)gr * NPAD + gc] = (bf16)(acc[mi][ni][i] * sc);
            }
        }
    }
}

// ---------------- gather core: lane c = lane*8, lanes 0..39 active, one dwordx4/edge ----------------
__device__ __forceinline__ void gather8(const bf16* __restrict__ m,
                                        const int* __restrict__ adj,
                                        int s, int d, int c, float acc[8]) {
    int e = 0;
    for (; e + 8 <= d; e += 8) {
        bf16x8 v0 = *(const bf16x8*)(m + (size_t)adj[s + e + 0] * NPAD + c);
        bf16x8 v1 = *(const bf16x8*)(m + (size_t)adj[s + e + 1] * NPAD + c);
        bf16x8 v2 = *(const bf16x8*)(m + (size_t)adj[s + e + 2] * NPAD + c);
        bf16x8 v3 = *(const bf16x8*)(m + (size_t)adj[s + e + 3] * NPAD + c);
        bf16x8 v4 = *(const bf16x8*)(m + (size_t)adj[s + e + 4] * NPAD + c);
        bf16x8 v5 = *(const bf16x8*)(m + (size_t)adj[s + e + 5] * NPAD + c);
        bf16x8 v6 = *(const bf16x8*)(m + (size_t)adj[s + e + 6] * NPAD + c);
        bf16x8 v7 = *(const bf16x8*)(m + (size_t)adj[s + e + 7] * NPAD + c);
#pragma unroll
        for (int q = 0; q < 8; ++q)
            acc[q] += ((float)v0[q] + (float)v1[q]) + ((float)v2[q] + (float)v3[q]) +
                      ((float)v4[q] + (float)v5[q]) + ((float)v6[q] + (float)v7[q]);
    }
    if (e + 4 <= d) {
        bf16x8 v0 = *(const bf16x8*)(m + (size_t)adj[s + e + 0] * NPAD + c);
        bf16x8 v1 = *(const bf16x8*)(m + (size_t)adj[s + e + 1] * NPAD + c);
        bf16x8 v2 = *(const bf16x8*)(m + (size_t)adj[s + e + 2] * NPAD + c);
        bf16x8 v3 = *(const bf16x8*)(m + (size_t)adj[s + e + 3] * NPAD + c);
#pragma unroll
        for (int q = 0; q < 8; ++q)
            acc[q] += ((float)v0[q] + (float)v1[q]) + ((float)v2[q] + (float)v3[q]);
        e += 4;
    }
    for (; e < d; ++e) {
        bf16x8 v = *(const bf16x8*)(m + (size_t)adj[s + e] * NPAD + c);
#pragma unroll
        for (int q = 0; q < 8; ++q) acc[q] += (float)v[q];
    }
}

// ---------------- layer-1 aggregation: h = relu(inv_in * sum m[adj] + bias) ----------------
__global__ __launch_bounds__(256) void aggregate_bf16(const bf16* __restrict__ m,
                                                      const int* __restrict__ row_start,
                                                      const int* __restrict__ deg_in,
                                                      const int* __restrict__ adj,
                                                      const float* __restrict__ inv_in,
                                                      const float* __restrict__ biasp,
                                                      bf16* __restrict__ h) {
    int node = (int)((blockIdx.x * (size_t)blockDim.x + threadIdx.x) >> 6);
    int lane = threadIdx.x & 63;
    if (node >= N_NODES) return;
    if (lane >= 40) return;
    int s = row_start[node];
    int d = deg_in[node];
    int c = lane * 8;
    float acc[8] = {};
    gather8(m, adj, s, d, c, acc);
    float sc = inv_in[node];
    float4 bq0 = *(const float4*)(biasp + c);
    float4 bq1 = *(const float4*)(biasp + c + 4);
    float bv[8] = {bq0.x, bq0.y, bq0.z, bq0.w, bq1.x, bq1.y, bq1.z, bq1.w};
    bf16x8 o;
#pragma unroll
    for (int q = 0; q < 8; ++q) o[q] = (bf16)fmaxf(acc[q] * sc + bv[q], 0.f);
    *(bf16x8*)(h + (size_t)node * NPAD + c) = o;
}

// ---------------- fused layer-2 aggregation + fc + softmax + pooling ----------------
__global__ __launch_bounds__(256) void agg2_fc_pool(const bf16* __restrict__ m,
                                                    const int* __restrict__ row_start,
                                                    const int* __restrict__ deg_in,
                                                    const int* __restrict__ adj,
                                                    const float* __restrict__ inv_in,
                                                    const float* __restrict__ biasp,
                                                    const float* __restrict__ wfcp,
                                                    const float* __restrict__ bfc,
                                                    const int* __restrict__ gid,
                                                    float* __restrict__ pooled,
                                                    int* __restrict__ gcount) {
    int node = (int)((blockIdx.x * (size_t)blockDim.x + threadIdx.x) >> 6);
    int lane = threadIdx.x & 63;
    if (node >= N_NODES) return;
    float z0 = 0.f, z1 = 0.f;
    if (lane < 40) {
        int s = row_start[node];
        int d = deg_in[node];
        int c = lane * 8;
        float acc[8] = {};
        gather8(m, adj, s, d, c, acc);
        float sc = inv_in[node];
        float4 bq0 = *(const float4*)(biasp + c);
        float4 bq1 = *(const float4*)(biasp + c + 4);
        float bv[8] = {bq0.x, bq0.y, bq0.z, bq0.w, bq1.x, bq1.y, bq1.z, bq1.w};
        // wfcp rows c..c+7, interleaved [col][2]
        float4 w0 = *(const float4*)(wfcp + c * 2);
        float4 w1 = *(const float4*)(wfcp + c * 2 + 4);
        float4 w2 = *(const float4*)(wfcp + c * 2 + 8);
        float4 w3 = *(const float4*)(wfcp + c * 2 + 12);
        float wz0[8] = {w0.x, w0.z, w1.x, w1.z, w2.x, w2.z, w3.x, w3.z};
        float wz1[8] = {w0.y, w0.w, w1.y, w1.w, w2.y, w2.w, w3.y, w3.w};
#pragma unroll
        for (int q = 0; q < 8; ++q) {
            float hq = fmaxf(acc[q] * sc + bv[q], 0.f);
            z0 += hq * wz0[q];
            z1 += hq * wz1[q];
        }
    }
    for (int off = 32; off; off >>= 1) {
        z0 += __shfl_down(z0, off);
        z1 += __shfl_down(z1, off);
    }
    if (lane == 0) {
        float s0 = z0 + bfc[0], s1 = z1 + bfc[1];
        float mx = fmaxf(s0, s1);
        float e0 = __expf(s0 - mx), e1 = __expf(s1 - mx);
        float inv = 1.f / (e0 + e1);
        int g = gid[node];
        atomicAdd(&pooled[g * 2 + 0], e0 * inv);
        atomicAdd(&pooled[g * 2 + 1], e1 * inv);
        atomicAdd(&gcount[g], 1);
    }
}

// ---------------- finalize: divide by counts ----------------
__global__ __launch_bounds__(256) void finalize(const float* __restrict__ pooled,
                                                const int* __restrict__ gcount,
                                                float* __restrict__ out) {
    int i = blockIdx.x * blockDim.x + threadIdx.x;
    if (i < N_GRAPHS * 2) {
        int g = i >> 1;
        float c = (float)max(gcount[g], 1);
        out[i] = pooled[i] / c;
    }
}

extern "C" void kernel_launch(void* const* d_in, const int* in_sizes, int n_in,
                              void* d_out, int out_size, void* d_ws, size_t ws_size,
                              hipStream_t stream) {
    const float* x   = (const float*)d_in[0];
    const float* W1  = (const float*)d_in[1];
    const float* b1  = (const float*)d_in[2];
    const float* W2  = (const float*)d_in[3];
    const float* b2  = (const float*)d_in[4];
    const float* Wfc = (const float*)d_in[5];
    const float* bfc = (const float*)d_in[6];
    const int* src   = (const int*)d_in[7];
    const int* dst   = (const int*)d_in[8];
    const int* gid   = (const int*)d_in[9];

    char* ws = (char*)d_ws;
    size_t off = 0;
    auto alloc = [&](size_t bytes) -> void* {
        void* p = ws + off;
        off = (off + bytes + 255) & ~(size_t)255;
        return p;
    };
    bf16* x_bf   = (bf16*)alloc((size_t)MPAD * K1PAD * 2);     // 128.1 MB
    bf16* h_bf   = (bf16*)alloc((size_t)MPAD * NPAD * 2);      // 64.1 MB
    bf16* m_bf   = (bf16*)alloc((size_t)N_NODES * NPAD * 2);   // 64.0 MB
    bf16* B1t    = (bf16*)alloc((size_t)NPAD * K1PAD * 2);
    bf16* B2t    = (bf16*)alloc((size_t)NPAD * K2PAD * 2);
    int*   adj      = (int*)alloc((size_t)N_EDGES * 4);
    int*   row_st   = (int*)alloc((size_t)N_NODES * 4);
    int*   cursor   = (int*)alloc((size_t)N_NODES * 4);
    int*   deg_in   = (int*)alloc((size_t)N_NODES * 4);
    int*   deg_out  = (int*)alloc((size_t)N_NODES * 4);
    float* inv_in   = (float*)alloc((size_t)N_NODES * 4);
    float* inv_out  = (float*)alloc((size_t)N_NODES * 4);
    const int NB = (N_NODES + 255) / 256;
    int*   bsum     = (int*)alloc((size_t)NB * 4);
    int*   boff     = (int*)alloc((size_t)NB * 4);
    float* pooled   = (float*)alloc((size_t)N_GRAPHS * 2 * 4);
    int*   gcount   = (int*)alloc((size_t)N_GRAPHS * 4);
    float* b1p      = (float*)alloc((size_t)NPAD * 4);
    float* b2p      = (float*)alloc((size_t)NPAD * 4);
    float* wfcp     = (float*)alloc((size_t)NPAD * 2 * 4);

    hipMemsetAsync(deg_in, 0, (size_t)N_NODES * 4, stream);
    hipMemsetAsync(deg_out, 0, (size_t)N_NODES * 4, stream);
    hipMemsetAsync(pooled, 0, (size_t)N_GRAPHS * 2 * 4, stream);
    hipMemsetAsync(gcount, 0, (size_t)N_GRAPHS * 4, stream);

    // graph preprocessing
    count_deg<<<(N_EDGES + 255) / 256, 256, 0, stream>>>(src, dst, deg_out, deg_in);
    block_sum<<<NB, 256, 0, stream>>>(deg_in, bsum);
    scan_serial<<<1, 64, 0, stream>>>(bsum, boff, NB);
    node_offsets<<<NB, 256, 0, stream>>>(deg_in, deg_out, boff, row_st, cursor, inv_in, inv_out);
    fill_csr<<<(N_EDGES + 255) / 256, 256, 0, stream>>>(src, dst, cursor, adj);

    // bf16 conversions + padded small tensors
    conv_x<<<(MPAD * (K1PAD / 8) + 255) / 256, 256, 0, stream>>>(x, x_bf);
    conv_bt<<<(NPAD * K1PAD + 255) / 256, 256, 0, stream>>>(W1, B1t, D_IN, D_H, K1PAD);
    conv_bt<<<(NPAD * K2PAD + 255) / 256, 256, 0, stream>>>(W2, B2t, D_H, D_H, K2PAD);
    prep_small<<<3, 256, 0, stream>>>(b1, b2, Wfc, b1p, b2p, wfcp);

    // layer 1
    mfma_gemm<<<MPAD / 128, 512, 0, stream>>>(x_bf, B1t, inv_out, m_bf, N_NODES, K1PAD);
    aggregate_bf16<<<(N_NODES * 64 + 255) / 256, 256, 0, stream>>>(m_bf, row_st, deg_in, adj, inv_in, b1p, h_bf);
    // layer 2
    mfma_gemm<<<MPAD / 128, 512, 0, stream>>>(h_bf, B2t, inv_out, m_bf, N_NODES, K2PAD);
    // fused layer-2 aggregate + fc + softmax + pooling
    agg2_fc_pool<<<(N_NODES * 64 + 255) / 256, 256, 0, stream>>>(m_bf, row_st, deg_in, adj, inv_in, b2p,
                                                                 wfcp, bfc, gid, pooled, gcount);
    finalize<<<(N_GRAPHS * 2 + 255) / 256, 256, 0, stream>>>(pooled, gcount, (float*)d_out);
}